// Round 5
// baseline (150.476 us; speedup 1.0000x reference)
//
#include <hip/hip_runtime.h>

#define BATCH 4
#define NDIM 2048
#define MDIM 2048
#define CDIM 128
#define NROWS (BATCH * NDIM)   // 8192 rows per tensor

typedef short bf16x8 __attribute__((ext_vector_type(8)));   // 8 bf16 (4 VGPRs)
typedef float f32x4  __attribute__((ext_vector_type(4)));   // MFMA accumulator
typedef float f32x2  __attribute__((ext_vector_type(2)));   // NT store payload

// fp32 -> bf16 bits, round-to-nearest-even (inputs are finite normals).
__device__ __forceinline__ unsigned short f2bf(float f) {
    union { float f; unsigned int u; } v; v.f = f;
    unsigned int u = v.u;
    return (unsigned short)((u + 0x7FFFu + ((u >> 16) & 1u)) >> 16);
}

// 16B global->LDS DMA (no VGPR round-trip). LDS dest must be
// wave-uniform base + lane*16 -- our tid*16 layout satisfies this.
__device__ __forceinline__ void gload_lds16(const void* g, void* l) {
    __builtin_amdgcn_global_load_lds(
        (const __attribute__((address_space(1))) void*)g,
        (__attribute__((address_space(3))) void*)l, 16, 0, 0);
}

// Kernel 1 (prep): per-row fp32 norms AND one-time fp32->bf16 conversion,
// rows written PRE-SWIZZLED in 16B chunks (chunk ^ (row&15)) so sim can
// global_load_lds them linearly and read fragments with the XOR pattern.
// 32 lanes per row (one float4 each). Runs at its read roofline (~11 us).
// ws layout: [0,2MB) src bf16 | [2MB,4MB) tgt bf16 | [4MB,+64KB) fp32 norms.
__global__ __launch_bounds__(256) void prep_kernel(
    const float* __restrict__ src, const float* __restrict__ tgt,
    unsigned short* __restrict__ bf, float* __restrict__ nrm)
{
    int gid = blockIdx.x * 256 + threadIdx.x;
    int row = gid >> 5;                 // 0..16383 (src then tgt)
    int l32 = gid & 31;
    const float* base = (row < NROWS)
        ? (src + (size_t)row * CDIM)
        : (tgt + (size_t)(row - NROWS) * CDIM);
    float4 v = ((const float4*)base)[l32];
    float s = v.x * v.x + v.y * v.y + v.z * v.z + v.w * v.w;
    #pragma unroll
    for (int off = 16; off >= 1; off >>= 1) s += __shfl_xor(s, off, 64);
    if (l32 == 0) nrm[row] = s;

    // swizzled bf16 store: chunk = 8 elems (16B); this lane owns half of one.
    int chunk = l32 >> 1;
    int half  = l32 & 1;
    unsigned short* dst = bf + (size_t)row * CDIM
                        + (((chunk ^ (row & 15)) << 3) + (half << 2));
    ushort4 u;
    u.x = f2bf(v.x); u.y = f2bf(v.y); u.z = f2bf(v.z); u.w = f2bf(v.w);
    *(ushort4*)dst = u;
}

// Kernel 2: 128x64 output tile (LDS 48 KiB -> 3 blocks/CU). Staging is pure
// global_load_lds DMA of pre-converted, pre-swizzled bf16 rows (zero staging
// VALU). Single isolated change vs R3: NONTEMPORAL output stores -- output
// is write-once; keep it from evicting the 4 MB bf16 working set out of L2.
__global__ __launch_bounds__(256, 3) void sim_mfma(
    const unsigned short* __restrict__ bfS, const unsigned short* __restrict__ bfT,
    const float* __restrict__ nrm, float* __restrict__ out)
{
    __shared__ unsigned short As[128 * 128];   // src tile (32 KiB)
    __shared__ unsigned short Bs[64 * 128];    // tgt tile (16 KiB)

    const int tid = threadIdx.x;
    const int b   = blockIdx.z;
    const int i0  = blockIdx.y << 7;   // src-row base (128 rows)
    const int j0  = blockIdx.x << 6;   // tgt-row base (64 rows)

    const char* gA = (const char*)(bfS + ((size_t)b * NDIM + i0) * CDIM);
    const char* gB = (const char*)(bfT + ((size_t)b * MDIM + j0) * CDIM);
    char* lA = (char*)As;
    char* lB = (char*)Bs;
    const int t16 = tid << 4;

    // A: 32 KiB = 8 x (256 threads x 16B); B: 16 KiB = 4 x.
    #pragma unroll
    for (int it = 0; it < 8; ++it)
        gload_lds16(gA + t16 + it * 4096, lA + t16 + it * 4096);
    #pragma unroll
    for (int it = 0; it < 4; ++it)
        gload_lds16(gB + t16 + it * 4096, lB + t16 + it * 4096);
    __syncthreads();

    const int wave = tid >> 6;
    const int lane = tid & 63;
    const int wm   = (wave & 1) << 6;   // 64-row half per wave
    const int wn   = (wave >> 1) << 5;  // 32-col half per wave
    const int l16  = lane & 15;
    const int q    = lane >> 4;

    // Norms (L2-hot).
    const float* nrmS = nrm + (size_t)b * NDIM + i0;
    const float* nrmT = nrm + (size_t)NROWS + (size_t)b * MDIM + j0;

    float sq[4][4], isq[4][4];
    #pragma unroll
    for (int i = 0; i < 4; ++i) {
        float4 s4v = *(const float4*)&nrmS[wm + (i << 4) + (q << 2)];
        sq[i][0] = s4v.x; sq[i][1] = s4v.y; sq[i][2] = s4v.z; sq[i][3] = s4v.w;
        #pragma unroll
        for (int r = 0; r < 4; ++r)
            isq[i][r] = __builtin_amdgcn_rsqf(fmaxf(sq[i][r], 1e-24f));
    }
    float tq[2], itq[2];
    #pragma unroll
    for (int jh = 0; jh < 2; ++jh) {
        tq[jh]  = nrmT[wn + (jh << 4) + l16];
        itq[jh] = __builtin_amdgcn_rsqf(fmaxf(tq[jh], 1e-24f));
    }

    f32x2* out2 = (f32x2*)out;

    // Two j-half phases: full K-loop then immediate store.
    #pragma unroll
    for (int jh = 0; jh < 2; ++jh) {
        f32x4 acc[4];
        #pragma unroll
        for (int i = 0; i < 4; ++i) acc[i] = (f32x4){0.f, 0.f, 0.f, 0.f};

        const int brow = wn + (jh << 4) + l16;
        #pragma unroll
        for (int k0 = 0; k0 < 4; ++k0) {
            int chunk = (k0 << 2) + q;           // (k0*32 + q*8) / 8
            int swz   = (chunk ^ l16) << 3;      // row%16 == l16
            bf16x8 bv = *(const bf16x8*)&Bs[brow * 128 + swz];
            #pragma unroll
            for (int i = 0; i < 4; ++i) {
                bf16x8 a = *(const bf16x8*)&As[(wm + (i << 4) + l16) * 128 + swz];
                acc[i] = __builtin_amdgcn_mfma_f32_16x16x32_bf16(a, bv, acc[i], 0, 0, 0);
            }
        }

        // Store this j-half (nontemporal). D: col = lane&15, row = q*4+reg.
        const int   ncol = wn + (jh << 4) + l16;
        const float tqj  = tq[jh], itj = itq[jh];
        #pragma unroll
        for (int i = 0; i < 4; ++i) {
            #pragma unroll
            for (int r = 0; r < 4; ++r) {
                int mrow = wm + (i << 4) + (q << 2) + r;
                size_t rowbase =
                    ((size_t)b * NDIM + (size_t)(i0 + mrow)) * MDIM + j0;
                float d   = acc[i][r];
                float cs  = d * isq[i][r] * itj;
                float dsq = fmaf(-2.0f, d, sq[i][r] + tqj);
                float fd  = __builtin_amdgcn_sqrtf(fmaxf(dsq, 0.0f));
                float fdn = __builtin_amdgcn_rcpf(1.0f + fd);
                f32x2 o; o.x = cs; o.y = fdn;
                __builtin_nontemporal_store(o, &out2[rowbase + ncol]);
            }
        }
    }
}

extern "C" void kernel_launch(void* const* d_in, const int* in_sizes, int n_in,
                              void* d_out, int out_size, void* d_ws, size_t ws_size,
                              hipStream_t stream) {
    const float* src = (const float*)d_in[0];
    const float* tgt = (const float*)d_in[1];
    float* out = (float*)d_out;

    unsigned short* bfS = (unsigned short*)d_ws;                 // 2 MiB
    unsigned short* bfT = bfS + (size_t)NROWS * CDIM;            // 2 MiB
    float*          nrm = (float*)(bfT + (size_t)NROWS * CDIM);  // 64 KiB

    // 16384 rows x 32 lanes = 524288 threads -> 2048 blocks.
    prep_kernel<<<dim3(2048), dim3(256), 0, stream>>>(src, tgt, bfS, nrm);

    dim3 grid(MDIM / 64, NDIM / 128, BATCH);
    sim_mfma<<<grid, dim3(256), 0, stream>>>(bfS, bfT, nrm, out);
}

// Round 6
// 143.662 us; speedup vs baseline: 1.0474x; 1.0474x over previous
//
#include <hip/hip_runtime.h>

#define BATCH 4
#define NDIM 2048
#define MDIM 2048
#define CDIM 128
#define NROWS (BATCH * NDIM)   // 8192 rows per tensor

typedef short bf16x8 __attribute__((ext_vector_type(8)));   // 8 bf16 (4 VGPRs)
typedef float f32x4  __attribute__((ext_vector_type(4)));   // MFMA accumulator
typedef float f32x2  __attribute__((ext_vector_type(2)));   // store payload

// fp32 -> bf16 bits, round-to-nearest-even (inputs are finite normals).
__device__ __forceinline__ unsigned short f2bf(float f) {
    union { float f; unsigned int u; } v; v.f = f;
    unsigned int u = v.u;
    return (unsigned short)((u + 0x7FFFu + ((u >> 16) & 1u)) >> 16);
}

// 16B global->LDS DMA (no VGPR round-trip). LDS dest must be
// wave-uniform base + lane*16 -- our tid*16 layout satisfies this.
__device__ __forceinline__ void gload_lds16(const void* g, void* l) {
    __builtin_amdgcn_global_load_lds(
        (const __attribute__((address_space(1))) void*)g,
        (__attribute__((address_space(3))) void*)l, 16, 0, 0);
}

// Kernel 1 (prep): per-row fp32 norms AND one-time fp32->bf16 conversion,
// rows written PRE-SWIZZLED in 16B chunks (chunk ^ (row&15)) so sim can
// global_load_lds them linearly and read fragments with the XOR pattern.
// Runs at its HBM read roofline (~10.5 us for 67 MB).
// ws layout: [0,2MB) src bf16 | [2MB,4MB) tgt bf16 | [4MB,+64KB) fp32 norms.
__global__ __launch_bounds__(256) void prep_kernel(
    const float* __restrict__ src, const float* __restrict__ tgt,
    unsigned short* __restrict__ bf, float* __restrict__ nrm)
{
    int gid = blockIdx.x * 256 + threadIdx.x;
    int row = gid >> 5;                 // 0..16383 (src then tgt)
    int l32 = gid & 31;
    const float* base = (row < NROWS)
        ? (src + (size_t)row * CDIM)
        : (tgt + (size_t)(row - NROWS) * CDIM);
    float4 v = ((const float4*)base)[l32];
    float s = v.x * v.x + v.y * v.y + v.z * v.z + v.w * v.w;
    #pragma unroll
    for (int off = 16; off >= 1; off >>= 1) s += __shfl_xor(s, off, 64);
    if (l32 == 0) nrm[row] = s;

    int chunk = l32 >> 1;
    int half  = l32 & 1;
    unsigned short* dst = bf + (size_t)row * CDIM
                        + (((chunk ^ (row & 15)) << 3) + (half << 2));
    ushort4 u;
    u.x = f2bf(v.x); u.y = f2bf(v.y); u.z = f2bf(v.z); u.w = f2bf(v.w);
    *(ushort4*)dst = u;
}

// Kernel 2: persistent-A j-strip blocks. 512 blocks = exactly 2/CU, ONE
// generation (no lockstep phase restarts -> store pipe never starves).
// Each block: stage 128-row A panel once, then 4 j-tiles of 64 cols with
// double-buffered B DMA prefetch hidden under the K-loop. Per-tile
// compute/epilogue identical to the verified R3 kernel. LDS 64 KiB.
__global__ __launch_bounds__(256, 2) void sim_mfma(
    const unsigned short* __restrict__ bfS, const unsigned short* __restrict__ bfT,
    const float* __restrict__ nrm, float* __restrict__ out)
{
    __shared__ unsigned short As[128 * 128];      // A panel (32 KiB)
    __shared__ unsigned short Bs[2][64 * 128];    // B double buffer (2x16 KiB)

    const int tid  = threadIdx.x;
    // 512 blocks = 8 XCDs x 64. Each XCD chunk: 8 contiguous A panels +
    // one batch's full tgt (~768 KB) -> L2-resident.
    const int flat = blockIdx.x;
    const int swb  = (flat & 7) * 64 + (flat >> 3);
    const int p    = swb >> 3;            // A-panel id 0..63
    const int js   = swb & 7;             // j-strip 0..7
    const int b    = p >> 4;              // batch
    const int i0   = (p & 15) << 7;       // src-row base (128 rows)
    const int j0s  = js << 8;             // strip base col (4 tiles x 64)

    const char* gA = (const char*)(bfS + ((size_t)b * NDIM + i0) * CDIM);
    const char* gB = (const char*)(bfT + (size_t)b * MDIM * CDIM);
    const int t16 = tid << 4;

    // Stage A (32 KiB = 8 x 256 threads x 16B) and B tile 0 (16 KiB).
    #pragma unroll
    for (int it = 0; it < 8; ++it)
        gload_lds16(gA + t16 + it * 4096, (char*)As + t16 + it * 4096);
    #pragma unroll
    for (int it = 0; it < 4; ++it)
        gload_lds16(gB + (size_t)j0s * 256 + t16 + it * 4096,
                    (char*)Bs[0] + t16 + it * 4096);

    const int wave = tid >> 6;
    const int lane = tid & 63;
    const int wm   = (wave & 1) << 6;   // 64-row half per wave
    const int wn   = (wave >> 1) << 5;  // 32-col half per wave
    const int l16  = lane & 15;
    const int q    = lane >> 4;

    // A-row norms (L2-hot, independent of LDS staging).
    const float* nrmS = nrm + (size_t)b * NDIM + i0;
    const float* nrmT = nrm + (size_t)NROWS + (size_t)b * MDIM;

    float sq[4][4], isq[4][4];
    #pragma unroll
    for (int i = 0; i < 4; ++i) {
        float4 s4v = *(const float4*)&nrmS[wm + (i << 4) + (q << 2)];
        sq[i][0] = s4v.x; sq[i][1] = s4v.y; sq[i][2] = s4v.z; sq[i][3] = s4v.w;
        #pragma unroll
        for (int r = 0; r < 4; ++r)
            isq[i][r] = __builtin_amdgcn_rsqf(fmaxf(sq[i][r], 1e-24f));
    }

    __syncthreads();   // A + B0 resident

    f32x2* out2 = (f32x2*)out;

    #pragma unroll
    for (int jt = 0; jt < 4; ++jt) {
        const int cur = jt & 1;            // compile-time after unroll
        // Prefetch next B tile into the other buffer; latency hides
        // under this tile's K-loop + epilogue.
        if (jt < 3) {
            const char* gBn = gB + (size_t)(j0s + ((jt + 1) << 6)) * 256;
            #pragma unroll
            for (int it = 0; it < 4; ++it)
                gload_lds16(gBn + t16 + it * 4096,
                            (char*)Bs[cur ^ 1] + t16 + it * 4096);
        }

        const int j0 = j0s + (jt << 6);
        const unsigned short* Bc = Bs[cur];

        // Two j-half phases: full K-loop then immediate store (R3 body).
        #pragma unroll
        for (int jh = 0; jh < 2; ++jh) {
            const float tqj = nrmT[j0 + wn + (jh << 4) + l16];
            const float itj = __builtin_amdgcn_rsqf(fmaxf(tqj, 1e-24f));

            f32x4 acc[4];
            #pragma unroll
            for (int i = 0; i < 4; ++i) acc[i] = (f32x4){0.f, 0.f, 0.f, 0.f};

            const int brow = wn + (jh << 4) + l16;
            #pragma unroll
            for (int k0 = 0; k0 < 4; ++k0) {
                int chunk = (k0 << 2) + q;           // (k0*32 + q*8) / 8
                int swz   = (chunk ^ l16) << 3;      // row%16 == l16
                bf16x8 bv = *(const bf16x8*)&Bc[brow * 128 + swz];
                #pragma unroll
                for (int i = 0; i < 4; ++i) {
                    bf16x8 a = *(const bf16x8*)&As[(wm + (i << 4) + l16) * 128 + swz];
                    acc[i] = __builtin_amdgcn_mfma_f32_16x16x32_bf16(a, bv, acc[i], 0, 0, 0);
                }
            }

            // Stores. D layout: col = lane&15, row = q*4 + reg.
            const int ncol = j0 + wn + (jh << 4) + l16;
            #pragma unroll
            for (int i = 0; i < 4; ++i) {
                #pragma unroll
                for (int r = 0; r < 4; ++r) {
                    int mrow = wm + (i << 4) + (q << 2) + r;
                    size_t rowbase =
                        ((size_t)b * NDIM + (size_t)(i0 + mrow)) * MDIM;
                    float d   = acc[i][r];
                    float cs  = d * isq[i][r] * itj;
                    float dsq = fmaf(-2.0f, d, sq[i][r] + tqj);
                    float fd  = __builtin_amdgcn_sqrtf(fmaxf(dsq, 0.0f));
                    float fdn = __builtin_amdgcn_rcpf(1.0f + fd);
                    f32x2 o; o.x = cs; o.y = fdn;
                    out2[rowbase + ncol] = o;
                }
            }
        }

        // Barrier (with its implicit vmcnt drain) before the next tile:
        // guarantees all waves' B-prefetch DMAs landed and all reads of
        // Bs[cur] finished before it is overwritten two tiles later.
        // The co-resident block covers this block's drain.
        if (jt < 3) __syncthreads();
    }
}

extern "C" void kernel_launch(void* const* d_in, const int* in_sizes, int n_in,
                              void* d_out, int out_size, void* d_ws, size_t ws_size,
                              hipStream_t stream) {
    const float* src = (const float*)d_in[0];
    const float* tgt = (const float*)d_in[1];
    float* out = (float*)d_out;

    unsigned short* bfS = (unsigned short*)d_ws;                 // 2 MiB
    unsigned short* bfT = bfS + (size_t)NROWS * CDIM;            // 2 MiB
    float*          nrm = (float*)(bfT + (size_t)NROWS * CDIM);  // 64 KiB

    // 16384 rows x 32 lanes = 524288 threads -> 2048 blocks.
    prep_kernel<<<dim3(2048), dim3(256), 0, stream>>>(src, tgt, bfS, nrm);

    // 512 persistent blocks (2/CU, one generation), XCD-chunk-swizzled.
    sim_mfma<<<dim3(512), dim3(256), 0, stream>>>(bfS, bfT, nrm, out);
}